// Round 5
// baseline (183.716 us; speedup 1.0000x reference)
//
#include <hip/hip_runtime.h>
#include <hip/hip_bf16.h>
#include <stdint.h>

#define SEQ   2048
#define DIM   512
#define BATCH 4

typedef __attribute__((ext_vector_type(8))) short  short8;
typedef __attribute__((ext_vector_type(4))) float  floatx4;

static __device__ __forceinline__ unsigned short f2b(float f) {
  return __builtin_bit_cast(unsigned short, __float2bfloat16(f));
}
static __device__ __forceinline__ float b2f(unsigned int lo16) {
  unsigned int v = lo16 << 16;
  return __builtin_bit_cast(float, v);
}

// async 16B/lane global->LDS (global_load_lds_dwordx4)
static __device__ __forceinline__ void gll16(const void* g, void* l) {
  __builtin_amdgcn_global_load_lds(
      (__attribute__((address_space(1))) void*)(uintptr_t)g,
      (__attribute__((address_space(3))) void*)l, 16, 0, 0);
}

// 128x128 tile GEMM mainloop, BK=32, 256 threads (4 waves as 2x2 of 64x64).
// A  : [128 rows][K] bf16 row-major (tile base applied), stride lda
// Bt : [128 cols][K] bf16 row-major ("B^T" layout), stride ldb
// LDS tiles: [128][32] bf16 row-major (64B rows), A then B.
// If RS, also accumulates per-lane partial row-sums of A fragments into rs[4]
// (row = wm + i*16 + (lane&15); complete after xor-16/32 butterfly).
template <bool RS>
__device__ __forceinline__ void gemm128_mainloop(
    const __hip_bfloat16* __restrict__ A, int lda,
    const __hip_bfloat16* __restrict__ Bt, int ldb,
    int kIters, char* ldsA, char* ldsB, floatx4 acc[4][4], float rs[4])
{
  const int tid  = threadIdx.x;
  const int lane = tid & 63;
  const int row  = tid >> 2;   // 0..63 (4 x 16B chunks per 64B row)
  const int kc   = tid & 3;
  const int wm   = ((tid >> 6) & 1) * 64;
  const int wn   = ((tid >> 6) >> 1) * 64;

  for (int kt = 0; kt < kIters; ++kt) {
    const int k0 = kt * 32 + kc * 8;
    gll16(A  + (size_t)row        * lda + k0, ldsA + tid * 16);
    gll16(A  + (size_t)(row + 64) * lda + k0, ldsA + 4096 + tid * 16);
    gll16(Bt + (size_t)row        * ldb + k0, ldsB + tid * 16);
    gll16(Bt + (size_t)(row + 64) * ldb + k0, ldsB + 4096 + tid * 16);
    __syncthreads();

    short8 af[4], bf[4];
#pragma unroll
    for (int i = 0; i < 4; ++i)
      af[i] = *(const short8*)(ldsA + (wm + i * 16 + (lane & 15)) * 64 + (lane >> 4) * 16);
#pragma unroll
    for (int j = 0; j < 4; ++j)
      bf[j] = *(const short8*)(ldsB + (wn + j * 16 + (lane & 15)) * 64 + (lane >> 4) * 16);

    if (RS) {
#pragma unroll
      for (int i = 0; i < 4; ++i)
#pragma unroll
        for (int e = 0; e < 8; ++e)
          rs[i] += b2f((unsigned short)af[i][e]);
    }

#pragma unroll
    for (int i = 0; i < 4; ++i)
#pragma unroll
      for (int j = 0; j < 4; ++j)
        acc[i][j] = __builtin_amdgcn_mfma_f32_16x16x32_bf16(af[i], bf[j], acc[i][j], 0, 0, 0);
    __syncthreads();
  }
}

// ---- K0a: X fp32 -> bf16 (row-major [8192][512]) --------------------------
__global__ __launch_bounds__(256) void convx_kernel(
    const float* __restrict__ X, __hip_bfloat16* __restrict__ Xb)
{
  const int i = blockIdx.x * 256 + threadIdx.x;   // 4 floats/thread
  float4 v = ((const float4*)X)[i];
  ushort4 o;
  o.x = f2b(v.x); o.y = f2b(v.y); o.z = f2b(v.z); o.w = f2b(v.w);
  ((ushort4*)Xb)[i] = o;
}

// ---- K0b: W[k][n] fp32 -> Wt[z][n][k] bf16 (transposed) -------------------
__global__ __launch_bounds__(256) void convw_kernel(
    const float* __restrict__ Wq, const float* __restrict__ Wk,
    const float* __restrict__ Wv, __hip_bfloat16* __restrict__ Wt3)
{
  const int z  = blockIdx.y;
  const float* W = (z == 0) ? Wq : (z == 1) ? Wk : Wv;
  const int id = blockIdx.x * 256 + threadIdx.x;   // k*512 + n
  const int k  = id >> 9, n = id & 511;
  Wt3[(size_t)z * DIM * DIM + (size_t)n * DIM + k] = __float2bfloat16(W[id]);
}

// ---- K1: fused QKV projection (z = 0:Q, 1:K, 2:V^T) -----------------------
__global__ __launch_bounds__(256) void qkv_kernel(
    const __hip_bfloat16* __restrict__ Xb, const __hip_bfloat16* __restrict__ Wt3,
    const float* __restrict__ bq, const float* __restrict__ bk, const float* __restrict__ bv,
    __hip_bfloat16* __restrict__ Qb, __hip_bfloat16* __restrict__ Kb,
    __hip_bfloat16* __restrict__ Vt)
{
  __shared__ char lds[16384];
  const int z = blockIdx.z;
  const __hip_bfloat16* A  = Xb + (size_t)blockIdx.x * 128 * DIM;
  const __hip_bfloat16* Bt = Wt3 + (size_t)z * DIM * DIM + (size_t)blockIdx.y * 128 * DIM;
  floatx4 acc[4][4] = {};
  gemm128_mainloop<false>(A, DIM, Bt, DIM, DIM / 32, lds, lds + 8192, acc, nullptr);

  const float* bias = (z == 0) ? bq : (z == 1) ? bk : bv;
  const int lane = threadIdx.x & 63, wid = threadIdx.x >> 6;
  const int wm = (wid & 1) * 64, wn = (wid >> 1) * 64;
#pragma unroll
  for (int i = 0; i < 4; ++i) {
    const int mb = blockIdx.x * 128 + wm + i * 16 + (lane >> 4) * 4;
#pragma unroll
    for (int j = 0; j < 4; ++j) {
      const int n = blockIdx.y * 128 + wn + j * 16 + (lane & 15);
      const float bn = bias[n];
      if (z == 2) {
        // V^T[b][n][s], 4 consecutive s per lane -> one 8B store
        const int b = mb >> 11, s = mb & 2047;
        ushort4 pk;
        pk.x = f2b(acc[i][j][0] + bn);
        pk.y = f2b(acc[i][j][1] + bn);
        pk.z = f2b(acc[i][j][2] + bn);
        pk.w = f2b(acc[i][j][3] + bn);
        *(ushort4*)((unsigned short*)Vt + ((size_t)b * DIM + n) * SEQ + s) = pk;
      } else {
        __hip_bfloat16* O = (z == 0) ? Qb : Kb;
#pragma unroll
        for (int r = 0; r < 4; ++r)
          O[(size_t)(mb + r) * DIM + n] = __float2bfloat16(acc[i][j][r] + bn);
      }
    }
  }
}

// ---- K2: Sc = exp(Q K^T / sqrt(512)), bf16 row-major [b][s][t] ------------
__global__ __launch_bounds__(256) void scores_kernel(
    const __hip_bfloat16* __restrict__ Qb, const __hip_bfloat16* __restrict__ Kb,
    __hip_bfloat16* __restrict__ Sc)
{
  __shared__ char lds[16384];
  const int b = blockIdx.z;
  const __hip_bfloat16* A  = Qb + ((size_t)b * SEQ + (size_t)blockIdx.x * 128) * DIM;
  const __hip_bfloat16* Bt = Kb + ((size_t)b * SEQ + (size_t)blockIdx.y * 128) * DIM;
  floatx4 acc[4][4] = {};
  gemm128_mainloop<false>(A, DIM, Bt, DIM, DIM / 32, lds, lds + 8192, acc, nullptr);

  __hip_bfloat16* O = Sc + (size_t)b * SEQ * SEQ;
  const float scale = 0.044194173824159216f;  // 1/sqrt(512)
  const int lane = threadIdx.x & 63, wid = threadIdx.x >> 6;
  const int wm = (wid & 1) * 64, wn = (wid >> 1) * 64;
#pragma unroll
  for (int i = 0; i < 4; ++i) {
    const int m = blockIdx.x * 128 + wm + i * 16 + (lane >> 4) * 4;
#pragma unroll
    for (int j = 0; j < 4; ++j) {
      const int t = blockIdx.y * 128 + wn + j * 16 + (lane & 15);
#pragma unroll
      for (int r = 0; r < 4; ++r)
        O[(size_t)(m + r) * SEQ + t] = __float2bfloat16(__expf(acc[i][j][r] * scale));
    }
  }
}

// ---- K3: split-K PV partials. z = b*4 + chunk (chunk = 512 t). ------------
//      Stores un-normalized fp32 partial C to Pbuf[chunk] and per-chunk
//      row-sums (from A fragments) to rowsumP[chunk]. No atomics. -----------
__global__ __launch_bounds__(256) void pv_kernel(
    const __hip_bfloat16* __restrict__ Sc, const __hip_bfloat16* __restrict__ Vt,
    float* __restrict__ Pbuf, float* __restrict__ rowsumP)
{
  __shared__ char lds[16384];
  const int b = blockIdx.z >> 2, c = blockIdx.z & 3;
  const __hip_bfloat16* A  = Sc + (size_t)b * SEQ * SEQ + (size_t)blockIdx.x * 128 * SEQ + c * 512;
  const __hip_bfloat16* Bt = Vt + (size_t)b * DIM * SEQ + (size_t)blockIdx.y * 128 * SEQ + c * 512;
  floatx4 acc[4][4] = {};
  float rs[4] = {0.f, 0.f, 0.f, 0.f};
  gemm128_mainloop<true>(A, SEQ, Bt, SEQ, 512 / 32, lds, lds + 8192, acc, rs);

  // complete row sums over this chunk's 512 t (combine 4 k-octet lane groups)
#pragma unroll
  for (int i = 0; i < 4; ++i) {
    rs[i] += __shfl_xor(rs[i], 16, 64);
    rs[i] += __shfl_xor(rs[i], 32, 64);
  }

  const int lane = threadIdx.x & 63, wid = threadIdx.x >> 6;
  const int wm = (wid & 1) * 64, wn = (wid >> 1) * 64;
  float* P = Pbuf + (size_t)c * 8192 * DIM;

  // rowsumP: lane holds rs for row wm+i*16+(lane&15); lanes 0..15 store
  // (waves with same wm and lanes 16+ duplicate the same values - benign).
  if (lane < 16) {
#pragma unroll
    for (int i = 0; i < 4; ++i)
      rowsumP[(size_t)c * 8192 + b * SEQ + blockIdx.x * 128 + wm + i * 16 + lane] = rs[i];
  }

#pragma unroll
  for (int i = 0; i < 4; ++i) {
    const int m = blockIdx.x * 128 + wm + i * 16 + (lane >> 4) * 4;
#pragma unroll
    for (int j = 0; j < 4; ++j) {
      const int n = blockIdx.y * 128 + wn + j * 16 + (lane & 15);
#pragma unroll
      for (int r = 0; r < 4; ++r)
        P[((size_t)b * SEQ + m + r) * DIM + n] = acc[i][j][r];
    }
  }
}

// ---- K4: out = (sum_c Pbuf[c]) / (sum_c rowsumP[c]) -----------------------
__global__ __launch_bounds__(256) void reduce_kernel(
    const float* __restrict__ Pbuf, const float* __restrict__ rowsumP,
    float* __restrict__ out)
{
  const int idx = blockIdx.x * 256 + threadIdx.x;  // one float4 of out
  const int m = idx >> 7;                          // global row 0..8191
  float4 a = ((const float4*)Pbuf)[idx];
  const float4 a1 = ((const float4*)(Pbuf + 1 * 8192 * DIM))[idx];
  const float4 a2 = ((const float4*)(Pbuf + 2 * 8192 * DIM))[idx];
  const float4 a3 = ((const float4*)(Pbuf + 3 * 8192 * DIM))[idx];
  a.x += a1.x + a2.x + a3.x;
  a.y += a1.y + a2.y + a3.y;
  a.z += a1.z + a2.z + a3.z;
  a.w += a1.w + a2.w + a3.w;
  const float s = rowsumP[m] + rowsumP[8192 + m] + rowsumP[16384 + m] + rowsumP[24576 + m];
  const float inv = 1.f / s;
  float4 o;
  o.x = a.x * inv; o.y = a.y * inv; o.z = a.z * inv; o.w = a.w * inv;
  ((float4*)out)[idx] = o;
}

extern "C" void kernel_launch(void* const* d_in, const int* in_sizes, int n_in,
                              void* d_out, int out_size, void* d_ws, size_t ws_size,
                              hipStream_t stream) {
  const float* X  = (const float*)d_in[0];
  const float* Wq = (const float*)d_in[1];
  const float* bq = (const float*)d_in[2];
  const float* Wk = (const float*)d_in[3];
  const float* bk = (const float*)d_in[4];
  const float* Wv = (const float*)d_in[5];
  const float* bv = (const float*)d_in[6];
  float* out = (float*)d_out;
  char* ws = (char*)d_ws;

  // workspace layout (bytes)
  __hip_bfloat16* Xb  = (__hip_bfloat16*)(ws + 0);           //  8 MB
  __hip_bfloat16* Wt3 = (__hip_bfloat16*)(ws + 8388608);     //  1.5 MB
  __hip_bfloat16* Qb  = (__hip_bfloat16*)(ws + 9961472);     //  8 MB
  __hip_bfloat16* Kb  = (__hip_bfloat16*)(ws + 18350080);    //  8 MB
  __hip_bfloat16* Vt  = (__hip_bfloat16*)(ws + 26738688);    //  8 MB
  __hip_bfloat16* Sc  = (__hip_bfloat16*)(ws + 35127296);    // 32 MB (exp scores)
  float*          Pbuf    = (float*)(ws + 68681728);         // 4 x 16.78 MB
  float*          rowsumP = (float*)(ws + 135790592);        // 4 x 32 KB

  convx_kernel<<<dim3(4096), 256, 0, stream>>>(X, Xb);
  convw_kernel<<<dim3(1024, 3), 256, 0, stream>>>(Wq, Wk, Wv, Wt3);
  qkv_kernel<<<dim3(64, 4, 3), 256, 0, stream>>>(Xb, Wt3, bq, bk, bv, Qb, Kb, Vt);
  scores_kernel<<<dim3(16, 16, 4), 256, 0, stream>>>(Qb, Kb, Sc);
  pv_kernel<<<dim3(16, 4, 16), 256, 0, stream>>>(Sc, Vt, Pbuf, rowsumP);
  reduce_kernel<<<dim3(4096), 256, 0, stream>>>(Pbuf, rowsumP, out);
}

// Round 6
// 174.224 us; speedup vs baseline: 1.0545x; 1.0545x over previous
//
#include <hip/hip_runtime.h>
#include <hip/hip_bf16.h>
#include <stdint.h>

#define SEQ   2048
#define DIM   512
#define BATCH 4

typedef __attribute__((ext_vector_type(8))) short  short8;
typedef __attribute__((ext_vector_type(4))) float  floatx4;

static __device__ __forceinline__ unsigned short f2b(float f) {
  return __builtin_bit_cast(unsigned short, __float2bfloat16(f));
}

// async 16B/lane global->LDS (global_load_lds_dwordx4)
static __device__ __forceinline__ void gll16(const void* g, void* l) {
  __builtin_amdgcn_global_load_lds(
      (__attribute__((address_space(1))) void*)(uintptr_t)g,
      (__attribute__((address_space(3))) void*)l, 16, 0, 0);
}

// 128x128 tile GEMM mainloop, BK=32, 256 threads (4 waves as 2x2 of 64x64),
// DOUBLE-BUFFERED LDS with issue-early staging:
//   per iter: ds_read frags from buf[p]  ->  issue gll16 for kt+1 into
//   buf[1-p]  ->  MFMA  ->  one __syncthreads.
// The loads are in flight across the whole ds_read+MFMA phase, so the
// vmcnt(0) drain at the barrier waits only residual latency (vs R1-R5 where
// loads were issued immediately before the barrier = full-latency stall).
// LDS: 2 x (A[128][32] 8KB + B[128][32] 8KB) = 32 KB.
__device__ __forceinline__ void gemm128_dbuf(
    const __hip_bfloat16* __restrict__ A, int lda,
    const __hip_bfloat16* __restrict__ Bt, int ldb,
    int kIters, char* lds, floatx4 acc[4][4])
{
  const int tid  = threadIdx.x;
  const int lane = tid & 63;
  const int row  = tid >> 2;   // 0..63 (4 x 16B chunks per 64B row)
  const int kc   = tid & 3;
  const int wm   = ((tid >> 6) & 1) * 64;
  const int wn   = ((tid >> 6) >> 1) * 64;

  // stage tile kt into buffer p
  auto stage = [&](int p, int kt) {
    const int k0 = kt * 32 + kc * 8;
    char* bA = lds + p * 16384;
    char* bB = bA + 8192;
    gll16(A  + (size_t)row        * lda + k0, bA + tid * 16);
    gll16(A  + (size_t)(row + 64) * lda + k0, bA + 4096 + tid * 16);
    gll16(Bt + (size_t)row        * ldb + k0, bB + tid * 16);
    gll16(Bt + (size_t)(row + 64) * ldb + k0, bB + 4096 + tid * 16);
  };

  stage(0, 0);
  __syncthreads();                       // buf0 ready

  for (int kt = 0; kt < kIters; ++kt) {
    const int p = kt & 1;
    const char* bA = lds + p * 16384;
    const char* bB = bA + 8192;

    short8 af[4], bf[4];
#pragma unroll
    for (int i = 0; i < 4; ++i)
      af[i] = *(const short8*)(bA + (wm + i * 16 + (lane & 15)) * 64 + (lane >> 4) * 16);
#pragma unroll
    for (int j = 0; j < 4; ++j)
      bf[j] = *(const short8*)(bB + (wn + j * 16 + (lane & 15)) * 64 + (lane >> 4) * 16);

    if (kt + 1 < kIters) stage(1 - p, kt + 1);   // issue-early into other buffer

#pragma unroll
    for (int i = 0; i < 4; ++i)
#pragma unroll
      for (int j = 0; j < 4; ++j)
        acc[i][j] = __builtin_amdgcn_mfma_f32_16x16x32_bf16(af[i], bf[j], acc[i][j], 0, 0, 0);

    __syncthreads();   // drains kt+1 loads (residual latency) + guards buf reuse
  }
}

// ---- K0a: X fp32 -> bf16 (row-major [8192][512]) --------------------------
__global__ __launch_bounds__(256) void convx_kernel(
    const float* __restrict__ X, __hip_bfloat16* __restrict__ Xb)
{
  const int i = blockIdx.x * 256 + threadIdx.x;   // 4 floats/thread
  float4 v = ((const float4*)X)[i];
  ushort4 o;
  o.x = f2b(v.x); o.y = f2b(v.y); o.z = f2b(v.z); o.w = f2b(v.w);
  ((ushort4*)Xb)[i] = o;
}

// ---- K0b: W[k][n] fp32 -> Wt[z][n][k] bf16 (transposed) -------------------
__global__ __launch_bounds__(256) void convw_kernel(
    const float* __restrict__ Wq, const float* __restrict__ Wk,
    const float* __restrict__ Wv, __hip_bfloat16* __restrict__ Wt3)
{
  const int z  = blockIdx.y;
  const float* W = (z == 0) ? Wq : (z == 1) ? Wk : Wv;
  const int id = blockIdx.x * 256 + threadIdx.x;   // k*512 + n
  const int k  = id >> 9, n = id & 511;
  Wt3[(size_t)z * DIM * DIM + (size_t)n * DIM + k] = __float2bfloat16(W[id]);
}

// ---- zero rowsum (8192 floats) --------------------------------------------
__global__ __launch_bounds__(256) void zfill_kernel(float4* __restrict__ p)
{
  p[blockIdx.x * 256 + threadIdx.x] = float4{0.f, 0.f, 0.f, 0.f};
}

// ---- K1: fused QKV projection (z = 0:Q, 1:K, 2:V^T) -----------------------
__global__ __launch_bounds__(256) void qkv_kernel(
    const __hip_bfloat16* __restrict__ Xb, const __hip_bfloat16* __restrict__ Wt3,
    const float* __restrict__ bq, const float* __restrict__ bk, const float* __restrict__ bv,
    __hip_bfloat16* __restrict__ Qb, __hip_bfloat16* __restrict__ Kb,
    __hip_bfloat16* __restrict__ Vt)
{
  __shared__ char lds[32768];
  const int z = blockIdx.z;
  const __hip_bfloat16* A  = Xb + (size_t)blockIdx.x * 128 * DIM;
  const __hip_bfloat16* Bt = Wt3 + (size_t)z * DIM * DIM + (size_t)blockIdx.y * 128 * DIM;
  floatx4 acc[4][4] = {};
  gemm128_dbuf(A, DIM, Bt, DIM, DIM / 32, lds, acc);

  const float* bias = (z == 0) ? bq : (z == 1) ? bk : bv;
  const int lane = threadIdx.x & 63, wid = threadIdx.x >> 6;
  const int wm = (wid & 1) * 64, wn = (wid >> 1) * 64;
#pragma unroll
  for (int i = 0; i < 4; ++i) {
    const int mb = blockIdx.x * 128 + wm + i * 16 + (lane >> 4) * 4;
#pragma unroll
    for (int j = 0; j < 4; ++j) {
      const int n = blockIdx.y * 128 + wn + j * 16 + (lane & 15);
      const float bn = bias[n];
      if (z == 2) {
        // V^T[b][n][s], 4 consecutive s per lane -> one 8B store
        const int b = mb >> 11, s = mb & 2047;
        ushort4 pk;
        pk.x = f2b(acc[i][j][0] + bn);
        pk.y = f2b(acc[i][j][1] + bn);
        pk.z = f2b(acc[i][j][2] + bn);
        pk.w = f2b(acc[i][j][3] + bn);
        *(ushort4*)((unsigned short*)Vt + ((size_t)b * DIM + n) * SEQ + s) = pk;
      } else {
        __hip_bfloat16* O = (z == 0) ? Qb : Kb;
#pragma unroll
        for (int r = 0; r < 4; ++r)
          O[(size_t)(mb + r) * DIM + n] = __float2bfloat16(acc[i][j][r] + bn);
      }
    }
  }
}

// ---- K2: Sc = exp(Q K^T / sqrt(512)) bf16 [b][s][t]; fused rowsum ---------
__global__ __launch_bounds__(256) void scores_kernel(
    const __hip_bfloat16* __restrict__ Qb, const __hip_bfloat16* __restrict__ Kb,
    __hip_bfloat16* __restrict__ Sc, float* __restrict__ rowsum)
{
  __shared__ char lds[32768];
  const int b = blockIdx.z;
  const __hip_bfloat16* A  = Qb + ((size_t)b * SEQ + (size_t)blockIdx.x * 128) * DIM;
  const __hip_bfloat16* Bt = Kb + ((size_t)b * SEQ + (size_t)blockIdx.y * 128) * DIM;
  floatx4 acc[4][4] = {};
  gemm128_dbuf(A, DIM, Bt, DIM, DIM / 32, lds, acc);

  __hip_bfloat16* O = Sc + (size_t)b * SEQ * SEQ;
  const float scale = 0.044194173824159216f;  // 1/sqrt(512)
  const int lane = threadIdx.x & 63, wid = threadIdx.x >> 6;
  const int wm = (wid & 1) * 64, wn = (wid >> 1) * 64;

  // overwrite acc with exp(scale * s), store bf16
#pragma unroll
  for (int i = 0; i < 4; ++i) {
    const int m = blockIdx.x * 128 + wm + i * 16 + (lane >> 4) * 4;
#pragma unroll
    for (int j = 0; j < 4; ++j) {
      const int t = blockIdx.y * 128 + wn + j * 16 + (lane & 15);
#pragma unroll
      for (int r = 0; r < 4; ++r) {
        acc[i][j][r] = __expf(acc[i][j][r] * scale);
        O[(size_t)(m + r) * SEQ + t] = __float2bfloat16(acc[i][j][r]);
      }
    }
  }

  // partial row sums over this block's 128 t: reduce over the 16 col-lanes
#pragma unroll
  for (int i = 0; i < 4; ++i) {
    const int mb = blockIdx.x * 128 + wm + i * 16 + (lane >> 4) * 4;
#pragma unroll
    for (int r = 0; r < 4; ++r) {
      float s = (acc[i][0][r] + acc[i][1][r]) + (acc[i][2][r] + acc[i][3][r]);
      s += __shfl_xor(s, 1, 64);
      s += __shfl_xor(s, 2, 64);
      s += __shfl_xor(s, 4, 64);
      s += __shfl_xor(s, 8, 64);
      if ((lane & 15) == 0)
        atomicAdd(rowsum + b * SEQ + mb + r, s);
    }
  }
}

// ---- K3: out[s][d] = (Sc . V) / rowsum[s] ---------------------------------
__global__ __launch_bounds__(256) void pv_kernel(
    const __hip_bfloat16* __restrict__ Sc, const __hip_bfloat16* __restrict__ Vt,
    const float* __restrict__ rowsum, float* __restrict__ out)
{
  __shared__ char lds[32768];
  const int b = blockIdx.z;
  const __hip_bfloat16* A  = Sc + (size_t)b * SEQ * SEQ + (size_t)blockIdx.x * 128 * SEQ;
  const __hip_bfloat16* Bt = Vt + (size_t)b * DIM * SEQ + (size_t)blockIdx.y * 128 * SEQ;
  floatx4 acc[4][4] = {};
  gemm128_dbuf(A, SEQ, Bt, SEQ, SEQ / 32, lds, acc);

  const int lane = threadIdx.x & 63, wid = threadIdx.x >> 6;
  const int wm = (wid & 1) * 64, wn = (wid >> 1) * 64;
#pragma unroll
  for (int i = 0; i < 4; ++i) {
    const int m = blockIdx.x * 128 + wm + i * 16 + (lane >> 4) * 4;
    const float4 rs = *(const float4*)(rowsum + b * SEQ + m);
    const float inv0 = 1.f / rs.x, inv1 = 1.f / rs.y, inv2 = 1.f / rs.z, inv3 = 1.f / rs.w;
#pragma unroll
    for (int j = 0; j < 4; ++j) {
      const int n = blockIdx.y * 128 + wn + j * 16 + (lane & 15);
      float* o = out + ((size_t)b * SEQ + m) * DIM + n;
      o[0 * DIM] = acc[i][j][0] * inv0;
      o[1 * DIM] = acc[i][j][1] * inv1;
      o[2 * DIM] = acc[i][j][2] * inv2;
      o[3 * DIM] = acc[i][j][3] * inv3;
    }
  }
}

extern "C" void kernel_launch(void* const* d_in, const int* in_sizes, int n_in,
                              void* d_out, int out_size, void* d_ws, size_t ws_size,
                              hipStream_t stream) {
  const float* X  = (const float*)d_in[0];
  const float* Wq = (const float*)d_in[1];
  const float* bq = (const float*)d_in[2];
  const float* Wk = (const float*)d_in[3];
  const float* bk = (const float*)d_in[4];
  const float* Wv = (const float*)d_in[5];
  const float* bv = (const float*)d_in[6];
  float* out = (float*)d_out;
  char* ws = (char*)d_ws;

  // workspace layout (bytes)
  __hip_bfloat16* Xb  = (__hip_bfloat16*)(ws + 0);           //  8 MB
  __hip_bfloat16* Wt3 = (__hip_bfloat16*)(ws + 8388608);     //  1.5 MB
  __hip_bfloat16* Qb  = (__hip_bfloat16*)(ws + 9961472);     //  8 MB
  __hip_bfloat16* Kb  = (__hip_bfloat16*)(ws + 18350080);    //  8 MB
  __hip_bfloat16* Vt  = (__hip_bfloat16*)(ws + 26738688);    //  8 MB
  __hip_bfloat16* Sc  = (__hip_bfloat16*)(ws + 35127296);    // 32 MB (exp scores)
  float*          rowsum = (float*)(ws + 68681728);          // 32 KB

  zfill_kernel<<<dim3(8), 256, 0, stream>>>((float4*)rowsum);
  convx_kernel<<<dim3(4096), 256, 0, stream>>>(X, Xb);
  convw_kernel<<<dim3(1024, 3), 256, 0, stream>>>(Wq, Wk, Wv, Wt3);
  qkv_kernel<<<dim3(64, 4, 3), 256, 0, stream>>>(Xb, Wt3, bq, bk, bv, Qb, Kb, Vt);
  scores_kernel<<<dim3(16, 16, 4), 256, 0, stream>>>(Qb, Kb, Sc, rowsum);
  pv_kernel<<<dim3(16, 4, 4), 256, 0, stream>>>(Sc, Vt, rowsum, out);
}